// Round 4
// baseline (256.359 us; speedup 1.0000x reference)
//
#include <hip/hip_runtime.h>
#include <cstdio>
#include <cstdint>

#define HH 512
#define WW 512
#define CC 32
#define BB 2
#define NN 120000
#define HWPIX (HH*WW)
#define NPTS (BB*NN)          // 240000 == total ranks (every point has a unique pixel)
#define NPIX (BB*HWPIX)       // 524288
#define NBLK (NPIX/256)       // 2048

__device__ __forceinline__ float dot4(float4 a, float4 b) {
    return a.x*b.x + a.y*b.y + a.z*b.z + a.w*b.w;
}
__device__ __forceinline__ void fma4(float4& o, float w, float4 v) {
    o.x += w*v.x; o.y += w*v.y; o.z += w*v.z; o.w += w*v.w;
}
__device__ __forceinline__ float4 fin4(float4 o, float wdy, float wdx, float woc, float rl,
                                       float4 py, float4 px, float4 pb, float4 b3) {
    float4 r;
    r.x = (o.x + wdy*py.x + wdx*px.x + woc*pb.x)*rl + b3.x;
    r.y = (o.y + wdy*py.y + wdx*px.y + woc*pb.y)*rl + b3.y;
    r.z = (o.z + wdy*py.z + wdx*px.z + woc*pb.z)*rl + b3.z;
    r.w = (o.w + wdy*py.w + wdx*px.w + woc*pb.w)*rl + b3.w;
    return r;
}

// ---------------- compose fused weight matrices ----------------
// M layout (floats): [0:1024) MqT, [1024:2048) MkT, [2048:3072) MvT, [3072:4096) owT
// MxT[j*32+c'] = (W_proj @ w_x)[c'][j];  owT[j*32+c'] = out_w[c'][j]
__global__ void compose_mats(const float* __restrict__ wq, const float* __restrict__ wk,
                             const float* __restrict__ wv, const float* __restrict__ in_w,
                             const float* __restrict__ out_w, float* __restrict__ M) {
    int tid = blockIdx.x * blockDim.x + threadIdx.x;   // 0..4095
    if (tid >= 4096) return;
    int which = tid >> 10;
    int e = tid & 1023;
    int cp = e & 31;
    int j  = e >> 5;
    if (which < 3) {
        const float* w = (which == 0) ? wq : ((which == 1) ? wk : wv);
        const float* Wrow = in_w + (which * 32 + cp) * 32;
        float acc = 0.f;
        #pragma unroll
        for (int t = 0; t < 32; ++t) acc += Wrow[t] * w[t * 32 + j];
        M[which * 1024 + j * 32 + cp] = acc;
    } else {
        M[3 * 1024 + j * 32 + cp] = out_w[cp * 32 + j];
    }
}

// V layout (floats): [0:32) bq' = W1@bq + in_b[:32], [32:64) bk' = W2@bk, [64:96) bv' = W3@bv,
// [96:128) PWy[c] = (W3@pos_w)[c][0], [128:160) PWx[c] = (W3@pos_w)[c][1], [160:192) pb3 = W3@pos_b
__global__ void compose_vecs(const float* __restrict__ bq, const float* __restrict__ bk,
                             const float* __restrict__ bv, const float* __restrict__ in_w,
                             const float* __restrict__ in_b, const float* __restrict__ pos_w,
                             const float* __restrict__ pos_b, float* __restrict__ V) {
    int tid = threadIdx.x;
    if (tid < 32) {
        float a = 0.f, b = 0.f, c = 0.f;
        #pragma unroll
        for (int t = 0; t < 32; ++t) {
            a += in_w[tid * 32 + t] * bq[t];
            b += in_w[(32 + tid) * 32 + t] * bk[t];
            c += in_w[(64 + tid) * 32 + t] * bv[t];
        }
        V[tid]      = a + in_b[tid];
        V[32 + tid] = b;
        V[64 + tid] = c;
    } else if (tid < 128) {
        int grp = (tid - 32) >> 5;   // 0=PWy 1=PWx 2=pb3
        int cp  = tid & 31;
        float acc = 0.f;
        #pragma unroll
        for (int t = 0; t < 32; ++t) {
            float src = (grp == 0) ? pos_w[t * 2 + 0] : ((grp == 1) ? pos_w[t * 2 + 1] : pos_b[t]);
            acc += in_w[(64 + cp) * 32 + t] * src;
        }
        V[96 + grp * 32 + cp] = acc;
    }
}

// ---------------- dense coord -> point-index grid ----------------
__global__ void build_grid(const int* __restrict__ coors, int* __restrict__ grid) {
    int P = blockIdx.x * blockDim.x + threadIdx.x;
    if (P >= NPTS) return;
    int b = P / NN;
    int n = P - b * NN;
    int y = coors[P * 2 + 0];
    int x = coors[P * 2 + 1];
    grid[b * HWPIX + y * WW + x] = n;
}

// ---------------- per-window occupied count ----------------
__global__ __launch_bounds__(256) void count_occ(const int* __restrict__ grid, int* __restrict__ cnt) {
    int tid = threadIdx.x;
    int pix = blockIdx.x * 256 + tid;
    bool occ = grid[pix] >= 0;
    unsigned long long mask = __ballot(occ);
    __shared__ int w[4];
    if ((tid & 63) == 0) w[tid >> 6] = __popcll(mask);
    __syncthreads();
    if (tid == 0) cnt[blockIdx.x] = w[0] + w[1] + w[2] + w[3];
}

// ---------------- exclusive scan of 2048 counts (single block) ----------------
__global__ __launch_bounds__(256) void scan2048(const int* __restrict__ cnt, int* __restrict__ off) {
    __shared__ int ps[256];
    int tid = threadIdx.x;
    int v[8], loc[8];
    int t = 0;
    #pragma unroll
    for (int k = 0; k < 8; ++k) { v[k] = cnt[tid * 8 + k]; loc[k] = t; t += v[k]; }
    ps[tid] = t;
    __syncthreads();
    for (int d = 1; d < 256; d <<= 1) {
        int val = ps[tid];
        int add = (tid >= d) ? ps[tid - d] : 0;
        __syncthreads();
        ps[tid] = val + add;
        __syncthreads();
    }
    int excl = (tid > 0) ? ps[tid - 1] : 0;
    #pragma unroll
    for (int k = 0; k < 8; ++k) off[tid * 8 + k] = excl + loc[k];
}

// ---------------- assign ranks: grid[pix]=rank, nlist[rank]=b*NN+n, plist[rank]=pix ----------------
__global__ __launch_bounds__(256) void assign_ranks(const int* __restrict__ off,
                                                    int* __restrict__ grid,
                                                    int* __restrict__ nlist,
                                                    int* __restrict__ plist) {
    __shared__ int woff[4];
    int tid = threadIdx.x;
    int pix = blockIdx.x * 256 + tid;
    int n = grid[pix];
    bool occ = n >= 0;
    unsigned long long mask = __ballot(occ);
    int lane = tid & 63, wvi = tid >> 6;
    if (lane == 0) woff[wvi] = __popcll(mask);
    __syncthreads();
    int pre = 0;
    for (int w = 0; w < wvi; ++w) pre += woff[w];
    if (occ) {
        int r = off[blockIdx.x] + pre + __popcll(mask & ((1ull << lane) - 1ull));
        grid[pix] = r;
        nlist[r] = (pix >> 18) * NN + n;
        plist[r] = pix;
    }
}

// ---------------- stage1: dense point-parallel LN + fused q/k/v linears ----------------
__global__ __launch_bounds__(256) void stage1(const float* __restrict__ feats,
                                              const float* __restrict__ ln_w,
                                              const float* __restrict__ ln_b,
                                              const float* __restrict__ M,
                                              const float* __restrict__ V,
                                              const int* __restrict__ nlist,
                                              float* __restrict__ qp,
                                              float* __restrict__ kv) {
    int r = blockIdx.x * 256 + threadIdx.x;
    bool active = r < NPTS;
    int gp = active ? nlist[r] : 0;

    const float* fr = feats + ((size_t)gp << 5);
    float x[32];
    #pragma unroll
    for (int k = 0; k < 8; ++k) ((float4*)x)[k] = ((const float4*)fr)[k];

    float s1 = 0.f, s2 = 0.f;
    #pragma unroll
    for (int j = 0; j < 32; ++j) { s1 += x[j]; s2 += x[j] * x[j]; }
    float mu   = s1 * (1.f / 32.f);
    float var  = s2 * (1.f / 32.f) - mu * mu;
    float rstd = rsqrtf(var + 1e-5f);
    #pragma unroll
    for (int j = 0; j < 32; ++j) x[j] = (x[j] - mu) * rstd * ln_w[j] + ln_b[j];

    float acc[32];

    // q' = x @ Mq + bq'
    #pragma unroll
    for (int c = 0; c < 32; ++c) acc[c] = V[c];
    #pragma unroll
    for (int j = 0; j < 32; ++j) {
        float xv = x[j];
        #pragma unroll
        for (int c = 0; c < 32; ++c) acc[c] += xv * M[j * 32 + c];
    }
    if (active) {
        float4* qd = (float4*)(qp + ((size_t)r << 5));
        #pragma unroll
        for (int k = 0; k < 8; ++k) qd[k] = ((float4*)acc)[k];
    }

    // k' = x @ Mk + bk'
    #pragma unroll
    for (int c = 0; c < 32; ++c) acc[c] = V[32 + c];
    #pragma unroll
    for (int j = 0; j < 32; ++j) {
        float xv = x[j];
        #pragma unroll
        for (int c = 0; c < 32; ++c) acc[c] += xv * M[1024 + j * 32 + c];
    }
    if (active) {
        float4* kd = (float4*)(kv + ((size_t)r << 6));
        #pragma unroll
        for (int k = 0; k < 8; ++k) kd[k] = ((float4*)acc)[k];
    }

    // v' = x @ Mv + bv'
    #pragma unroll
    for (int c = 0; c < 32; ++c) acc[c] = V[64 + c];
    #pragma unroll
    for (int j = 0; j < 32; ++j) {
        float xv = x[j];
        #pragma unroll
        for (int c = 0; c < 32; ++c) acc[c] += xv * M[2048 + j * 32 + c];
    }
    if (active) {
        float4* vd = (float4*)(kv + ((size_t)r << 6) + 32);
        #pragma unroll
        for (int k = 0; k < 8; ++k) vd[k] = ((float4*)acc)[k];
    }
}

// ---------------- stage2: dense (rank,head)-parallel attention + in-register out-proj ----------------
// Thread pair (even,odd lane) = the two heads of one point. No LDS.
// Overwrites qp[rank] with the projected output row.
__global__ __launch_bounds__(256) void stage2(const int* __restrict__ grid,
                                              const int* __restrict__ plist,
                                              const float* __restrict__ kv,
                                              const float* __restrict__ M,
                                              const float* __restrict__ V,
                                              const float* __restrict__ in_b,
                                              const float* __restrict__ out_b,
                                              float* __restrict__ qp) {
    int t = blockIdx.x * 256 + threadIdx.x;   // 0 .. 2*NPTS-1 (grid sized exactly)
    int r = t >> 1, h = t & 1;

    int pix = plist[r];
    int b = pix >> 18;
    int p = pix & (HWPIX - 1);
    int y = p >> 9, x = p & 511;

    const int DYC[9] = {0,-1,1,0,-1,1,0,-1,1};
    const int DXC[9] = {0,0,0,1,1,1,-1,-1,-1};

    const float4* q4 = (const float4*)(qp + ((size_t)r << 5) + (h << 4));
    float4 qA = q4[0], qB = q4[1], qC = q4[2], qD = q4[3];
    const float4* ib2 = (const float4*)(in_b + 32 + (h << 4));
    float eb = dot4(qA, ib2[0]) + dot4(qB, ib2[1]) + dot4(qC, ib2[2]) + dot4(qD, ib2[3]);

    float lg[9];
    int nr[9];
    #pragma unroll
    for (int s = 0; s < 9; ++s) {
        int sy = y + DYC[s], sx = x + DXC[s];
        int tr = -1;
        if (sy >= 0 && sy < HH && sx >= 0 && sx < WW)
            tr = grid[(b << 18) + (sy << 9) + sx];
        nr[s] = tr;
        float d = eb;
        if (tr >= 0) {
            const float4* kp = (const float4*)(kv + ((size_t)tr << 6) + (h << 4));
            float4 k0 = kp[0], k1 = kp[1], k2 = kp[2], k3 = kp[3];
            d += dot4(qA, k0) + dot4(qB, k1) + dot4(qC, k2) + dot4(qD, k3);
        }
        lg[s] = d * 0.25f;   // 1/sqrt(HD=16)
    }
    float m = lg[0];
    #pragma unroll
    for (int s = 1; s < 9; ++s) m = fmaxf(m, lg[s]);
    float l = 0.f;
    #pragma unroll
    for (int s = 0; s < 9; ++s) { lg[s] = __expf(lg[s] - m); l += lg[s]; }

    float4 oA = {0,0,0,0}, oB = {0,0,0,0}, oC = {0,0,0,0}, oD = {0,0,0,0};
    float wdy = 0.f, wdx = 0.f, woc = 0.f;
    #pragma unroll
    for (int s = 0; s < 9; ++s) {
        if (nr[s] >= 0) {
            float w = lg[s];
            const float4* vp = (const float4*)(kv + ((size_t)nr[s] << 6) + 32 + (h << 4));
            float4 v0 = vp[0], v1 = vp[1], v2 = vp[2], v3 = vp[3];
            fma4(oA, w, v0); fma4(oB, w, v1); fma4(oC, w, v2); fma4(oD, w, v3);
            wdy += w * (float)DYC[s];
            wdx += w * (float)DXC[s];
            woc += w;
        }
    }
    float rl = 1.f / l;
    const float4* PY = (const float4*)(V + 96 + (h << 4));
    const float4* PX = (const float4*)(V + 128 + (h << 4));
    const float4* PB = (const float4*)(V + 160 + (h << 4));
    const float4* B3 = (const float4*)(in_b + 64 + (h << 4));
    float o16[16];
    ((float4*)o16)[0] = fin4(oA, wdy, wdx, woc, rl, PY[0], PX[0], PB[0], B3[0]);
    ((float4*)o16)[1] = fin4(oB, wdy, wdx, woc, rl, PY[1], PX[1], PB[1], B3[1]);
    ((float4*)o16)[2] = fin4(oC, wdy, wdx, woc, rl, PY[2], PX[2], PB[2], B3[2]);
    ((float4*)o16)[3] = fin4(oD, wdy, wdx, woc, rl, PY[3], PX[3], PB[3], B3[3]);

    // exchange halves with partner lane (head pair on adjacent lanes)
    float of0[16], of1[16];
    #pragma unroll
    for (int j = 0; j < 16; ++j) {
        float po = __shfl_xor(o16[j], 1, 64);
        of0[j] = h ? po : o16[j];
        of1[j] = h ? o16[j] : po;
    }

    // out projection: both lanes compute all 32 channels with uniform (scalar) weights
    float acc[32];
    #pragma unroll
    for (int c = 0; c < 32; ++c) acc[c] = out_b[c];
    #pragma unroll
    for (int j = 0; j < 16; ++j) {
        float v0 = of0[j];
        #pragma unroll
        for (int c = 0; c < 32; ++c) acc[c] += v0 * M[3072 + j * 32 + c];
    }
    #pragma unroll
    for (int j = 0; j < 16; ++j) {
        float v1 = of1[j];
        #pragma unroll
        for (int c = 0; c < 32; ++c) acc[c] += v1 * M[3072 + (16 + j) * 32 + c];
    }

    // each lane stores its own 16 channels (pair writes one contiguous 128 B row)
    float st[16];
    #pragma unroll
    for (int k = 0; k < 16; ++k) st[k] = h ? acc[16 + k] : acc[k];
    float4* dst = (float4*)(qp + ((size_t)r << 5) + (h << 4));
    #pragma unroll
    for (int k = 0; k < 4; ++k) dst[k] = ((float4*)st)[k];
}

// ---------------- stage3: full-canvas write (rank reads are coalesced) ----------------
__global__ __launch_bounds__(256) void stage3(const int* __restrict__ grid,
                                              const float* __restrict__ obuf,
                                              float* __restrict__ out) {
    int t = blockIdx.x * blockDim.x + threadIdx.x;
    int b = t >> 18;
    int p = t & (HWPIX - 1);
    int rk = grid[t];
    float r[32];
    if (rk >= 0) {
        const float4* row = (const float4*)(obuf + ((size_t)rk << 5));
        #pragma unroll
        for (int i = 0; i < 8; ++i) ((float4*)r)[i] = row[i];
    } else {
        #pragma unroll
        for (int i = 0; i < 32; ++i) r[i] = 0.f;
    }
    float* outb = out + (size_t)b * CC * HWPIX + p;
    #pragma unroll
    for (int cc = 0; cc < 32; ++cc) outb[cc * HWPIX] = r[cc];
}

extern "C" void kernel_launch(void* const* d_in, const int* in_sizes, int n_in,
                              void* d_out, int out_size, void* d_ws, size_t ws_size,
                              hipStream_t stream) {
    const float* feats = (const float*)d_in[0];
    const int*   coors = (const int*)d_in[1];
    const float* ln_w  = (const float*)d_in[2];
    const float* ln_b  = (const float*)d_in[3];
    const float* wq    = (const float*)d_in[4];
    const float* bq    = (const float*)d_in[5];
    const float* wk    = (const float*)d_in[6];
    const float* bk    = (const float*)d_in[7];
    const float* wv    = (const float*)d_in[8];
    const float* bv    = (const float*)d_in[9];
    const float* pos_w = (const float*)d_in[10];
    const float* pos_b = (const float*)d_in[11];
    const float* in_w  = (const float*)d_in[12];
    const float* in_b  = (const float*)d_in[13];
    const float* out_w = (const float*)d_in[14];
    const float* out_b = (const float*)d_in[15];

    // workspace layout
    int*   grid = (int*)d_ws;                               // NPIX ints
    float* qp   = (float*)d_ws + NPIX;                      // NPTS*32 (reused as projected o)
    float* kv   = qp + (size_t)NPTS * 32;                   // NPTS*64 interleaved k|v
    float* M    = kv + (size_t)NPTS * 64;                   // 4096
    float* V    = M + 4096;                                 // 192
    size_t need = ((size_t)NPIX + (size_t)NPTS * 96 + 4096 + 192) * sizeof(float);
    if (ws_size < need) {
        fprintf(stderr, "kernel_launch: ws too small: %zu < %zu\n", ws_size, need);
        return;
    }
    // scratch in the tail of d_out (stage3 rewrites all of d_out at the end):
    //   [out_size-4096, -2048): cnt   [-2048, end): off
    //   [out_size-4096-2*NPTS, -4096): nlist | plist
    int* cnt   = (int*)d_out + (out_size - 4096);
    int* off   = cnt + 2048;
    int* nlist = (int*)d_out + (out_size - 4096 - 2 * NPTS);
    int* plist = nlist + NPTS;

    hipMemsetAsync(grid, 0xFF, (size_t)NPIX * sizeof(int), stream);   // grid = -1
    compose_mats<<<16, 256, 0, stream>>>(wq, wk, wv, in_w, out_w, M);
    compose_vecs<<<1, 128, 0, stream>>>(bq, bk, bv, in_w, in_b, pos_w, pos_b, V);
    build_grid<<<(NPTS + 255) / 256, 256, 0, stream>>>(coors, grid);
    count_occ<<<NBLK, 256, 0, stream>>>(grid, cnt);
    scan2048<<<1, 256, 0, stream>>>(cnt, off);
    assign_ranks<<<NBLK, 256, 0, stream>>>(off, grid, nlist, plist);
    stage1<<<(NPTS + 255) / 256, 256, 0, stream>>>(feats, ln_w, ln_b, M, V, nlist, qp, kv);
    stage2<<<(2 * NPTS) / 256, 256, 0, stream>>>(grid, plist, kv, M, V, in_b, out_b, qp);
    stage3<<<NBLK, 256, 0, stream>>>(grid, qp, (float*)d_out);
}

// Round 5
// 246.061 us; speedup vs baseline: 1.0418x; 1.0418x over previous
//
#include <hip/hip_runtime.h>
#include <cstdio>
#include <cstdint>

#define HH 512
#define WW 512
#define CC 32
#define BB 2
#define NN 120000
#define HWPIX (HH*WW)
#define NPTS (BB*NN)          // 240000 == total ranks (every point has a unique pixel)
#define NPIX (BB*HWPIX)       // 524288
#define NBLK (NPIX/256)       // 2048

__device__ __forceinline__ float dot4(float4 a, float4 b) {
    return a.x*b.x + a.y*b.y + a.z*b.z + a.w*b.w;
}
__device__ __forceinline__ void fma4(float4& o, float w, float4 v) {
    o.x += w*v.x; o.y += w*v.y; o.z += w*v.z; o.w += w*v.w;
}
__device__ __forceinline__ float4 fin4(float4 o, float wdy, float wdx, float woc, float rl,
                                       float4 py, float4 px, float4 pb, float4 b3) {
    float4 r;
    r.x = (o.x + wdy*py.x + wdx*px.x + woc*pb.x)*rl + b3.x;
    r.y = (o.y + wdy*py.y + wdx*px.y + woc*pb.y)*rl + b3.y;
    r.z = (o.z + wdy*py.z + wdx*px.z + woc*pb.z)*rl + b3.z;
    r.w = (o.w + wdy*py.w + wdx*px.w + woc*pb.w)*rl + b3.w;
    return r;
}

// ---------------- compose fused weight matrices ----------------
// M layout (floats): [0:1024) MqT, [1024:2048) MkT, [2048:3072) MvT, [3072:4096) owT
// MxT[j*32+c'] = (W_proj @ w_x)[c'][j];  owT[j*32+c'] = out_w[c'][j]
__global__ void compose_mats(const float* __restrict__ wq, const float* __restrict__ wk,
                             const float* __restrict__ wv, const float* __restrict__ in_w,
                             const float* __restrict__ out_w, float* __restrict__ M) {
    int tid = blockIdx.x * blockDim.x + threadIdx.x;   // 0..4095
    if (tid >= 4096) return;
    int which = tid >> 10;
    int e = tid & 1023;
    int cp = e & 31;
    int j  = e >> 5;
    if (which < 3) {
        const float* w = (which == 0) ? wq : ((which == 1) ? wk : wv);
        const float* Wrow = in_w + (which * 32 + cp) * 32;
        float acc = 0.f;
        #pragma unroll
        for (int t = 0; t < 32; ++t) acc += Wrow[t] * w[t * 32 + j];
        M[which * 1024 + j * 32 + cp] = acc;
    } else {
        M[3 * 1024 + j * 32 + cp] = out_w[cp * 32 + j];
    }
}

// V layout (floats): [0:32) bq' = W1@bq + in_b[:32], [32:64) bk' = W2@bk, [64:96) bv' = W3@bv,
// [96:128) PWy[c] = (W3@pos_w)[c][0], [128:160) PWx[c] = (W3@pos_w)[c][1], [160:192) pb3 = W3@pos_b
__global__ void compose_vecs(const float* __restrict__ bq, const float* __restrict__ bk,
                             const float* __restrict__ bv, const float* __restrict__ in_w,
                             const float* __restrict__ in_b, const float* __restrict__ pos_w,
                             const float* __restrict__ pos_b, float* __restrict__ V) {
    int tid = threadIdx.x;
    if (tid < 32) {
        float a = 0.f, b = 0.f, c = 0.f;
        #pragma unroll
        for (int t = 0; t < 32; ++t) {
            a += in_w[tid * 32 + t] * bq[t];
            b += in_w[(32 + tid) * 32 + t] * bk[t];
            c += in_w[(64 + tid) * 32 + t] * bv[t];
        }
        V[tid]      = a + in_b[tid];
        V[32 + tid] = b;
        V[64 + tid] = c;
    } else if (tid < 128) {
        int grp = (tid - 32) >> 5;   // 0=PWy 1=PWx 2=pb3
        int cp  = tid & 31;
        float acc = 0.f;
        #pragma unroll
        for (int t = 0; t < 32; ++t) {
            float src = (grp == 0) ? pos_w[t * 2 + 0] : ((grp == 1) ? pos_w[t * 2 + 1] : pos_b[t]);
            acc += in_w[(64 + cp) * 32 + t] * src;
        }
        V[96 + grp * 32 + cp] = acc;
    }
}

// ---------------- dense coord -> point-index grid ----------------
__global__ void build_grid(const int* __restrict__ coors, int* __restrict__ grid) {
    int P = blockIdx.x * blockDim.x + threadIdx.x;
    if (P >= NPTS) return;
    int b = P / NN;
    int n = P - b * NN;
    int y = coors[P * 2 + 0];
    int x = coors[P * 2 + 1];
    grid[b * HWPIX + y * WW + x] = n;
}

// ---------------- per-window occupied count ----------------
__global__ __launch_bounds__(256) void count_occ(const int* __restrict__ grid, int* __restrict__ cnt) {
    int tid = threadIdx.x;
    int pix = blockIdx.x * 256 + tid;
    bool occ = grid[pix] >= 0;
    unsigned long long mask = __ballot(occ);
    __shared__ int w[4];
    if ((tid & 63) == 0) w[tid >> 6] = __popcll(mask);
    __syncthreads();
    if (tid == 0) cnt[blockIdx.x] = w[0] + w[1] + w[2] + w[3];
}

// ---------------- exclusive scan of 2048 counts (single block) ----------------
__global__ __launch_bounds__(256) void scan2048(const int* __restrict__ cnt, int* __restrict__ off) {
    __shared__ int ps[256];
    int tid = threadIdx.x;
    int v[8], loc[8];
    int t = 0;
    #pragma unroll
    for (int k = 0; k < 8; ++k) { v[k] = cnt[tid * 8 + k]; loc[k] = t; t += v[k]; }
    ps[tid] = t;
    __syncthreads();
    for (int d = 1; d < 256; d <<= 1) {
        int val = ps[tid];
        int add = (tid >= d) ? ps[tid - d] : 0;
        __syncthreads();
        ps[tid] = val + add;
        __syncthreads();
    }
    int excl = (tid > 0) ? ps[tid - 1] : 0;
    #pragma unroll
    for (int k = 0; k < 8; ++k) off[tid * 8 + k] = excl + loc[k];
}

// ---------------- assign ranks: grid[pix]=rank, nlist[rank]=b*NN+n, plist[rank]=pix ----------------
__global__ __launch_bounds__(256) void assign_ranks(const int* __restrict__ off,
                                                    int* __restrict__ grid,
                                                    int* __restrict__ nlist,
                                                    int* __restrict__ plist) {
    __shared__ int woff[4];
    int tid = threadIdx.x;
    int pix = blockIdx.x * 256 + tid;
    int n = grid[pix];
    bool occ = n >= 0;
    unsigned long long mask = __ballot(occ);
    int lane = tid & 63, wvi = tid >> 6;
    if (lane == 0) woff[wvi] = __popcll(mask);
    __syncthreads();
    int pre = 0;
    for (int w = 0; w < wvi; ++w) pre += woff[w];
    if (occ) {
        int r = off[blockIdx.x] + pre + __popcll(mask & ((1ull << lane) - 1ull));
        grid[pix] = r;
        nlist[r] = (pix >> 18) * NN + n;
        plist[r] = pix;
    }
}

// ---------------- stage1: dense point-parallel LN + fused q/k/v linears ----------------
// XCD-swizzled: XCD x covers ranks [x*118*256, ...) to match stage2's stripes.
__global__ __launch_bounds__(256) void stage1(const float* __restrict__ feats,
                                              const float* __restrict__ ln_w,
                                              const float* __restrict__ ln_b,
                                              const float* __restrict__ M,
                                              const float* __restrict__ V,
                                              const int* __restrict__ nlist,
                                              float* __restrict__ qp,
                                              float* __restrict__ kv) {
    int w = (blockIdx.x & 7) * 118 + (blockIdx.x >> 3);   // G=944
    if (w >= 938) return;
    int r = w * 256 + threadIdx.x;
    bool active = r < NPTS;
    int gp = active ? nlist[r] : 0;

    const float* fr = feats + ((size_t)gp << 5);
    float x[32];
    #pragma unroll
    for (int k = 0; k < 8; ++k) ((float4*)x)[k] = ((const float4*)fr)[k];

    float s1 = 0.f, s2 = 0.f;
    #pragma unroll
    for (int j = 0; j < 32; ++j) { s1 += x[j]; s2 += x[j] * x[j]; }
    float mu   = s1 * (1.f / 32.f);
    float var  = s2 * (1.f / 32.f) - mu * mu;
    float rstd = rsqrtf(var + 1e-5f);
    #pragma unroll
    for (int j = 0; j < 32; ++j) x[j] = (x[j] - mu) * rstd * ln_w[j] + ln_b[j];

    float acc[32];

    // q' = x @ Mq + bq'
    #pragma unroll
    for (int c = 0; c < 32; ++c) acc[c] = V[c];
    #pragma unroll
    for (int j = 0; j < 32; ++j) {
        float xv = x[j];
        #pragma unroll
        for (int c = 0; c < 32; ++c) acc[c] += xv * M[j * 32 + c];
    }
    if (active) {
        float4* qd = (float4*)(qp + ((size_t)r << 5));
        #pragma unroll
        for (int k = 0; k < 8; ++k) qd[k] = ((float4*)acc)[k];
    }

    // k' = x @ Mk + bk'
    #pragma unroll
    for (int c = 0; c < 32; ++c) acc[c] = V[32 + c];
    #pragma unroll
    for (int j = 0; j < 32; ++j) {
        float xv = x[j];
        #pragma unroll
        for (int c = 0; c < 32; ++c) acc[c] += xv * M[1024 + j * 32 + c];
    }
    if (active) {
        float4* kd = (float4*)(kv + ((size_t)r << 6));
        #pragma unroll
        for (int k = 0; k < 8; ++k) kd[k] = ((float4*)acc)[k];
    }

    // v' = x @ Mv + bv'
    #pragma unroll
    for (int c = 0; c < 32; ++c) acc[c] = V[64 + c];
    #pragma unroll
    for (int j = 0; j < 32; ++j) {
        float xv = x[j];
        #pragma unroll
        for (int c = 0; c < 32; ++c) acc[c] += xv * M[2048 + j * 32 + c];
    }
    if (active) {
        float4* vd = (float4*)(kv + ((size_t)r << 6) + 32);
        #pragma unroll
        for (int k = 0; k < 8; ++k) vd[k] = ((float4*)acc)[k];
    }
}

// ---------------- stage2: dense (rank,head)-parallel attention + out-proj ----------------
// Thread pair (even,odd lane) = the two heads of one point. Output staged through LDS
// so global stores are per-instruction wave-contiguous. XCD-swizzled stripes.
// Overwrites qp[rank] with the projected output row.
__global__ __launch_bounds__(256) void stage2(const int* __restrict__ grid,
                                              const int* __restrict__ plist,
                                              const float* __restrict__ kv,
                                              const float* __restrict__ M,
                                              const float* __restrict__ V,
                                              const float* __restrict__ in_b,
                                              const float* __restrict__ out_b,
                                              float* __restrict__ qp) {
    __shared__ float lds[128 * 36];   // 18 KB; row stride 36 keeps float4 alignment

    int w = (blockIdx.x & 7) * 235 + (blockIdx.x >> 3);   // G=1880; XCD x -> ranks [x*30080, +30080)
    if (w >= 1875) return;                                 // 1875*256 == 2*NPTS exactly
    int t = w * 256 + threadIdx.x;
    int r = t >> 1, h = t & 1;

    int pix = plist[r];
    int b = pix >> 18;
    int p = pix & (HWPIX - 1);
    int y = p >> 9, x = p & 511;

    const int DYC[9] = {0,-1,1,0,-1,1,0,-1,1};
    const int DXC[9] = {0,0,0,1,1,1,-1,-1,-1};

    const float4* q4 = (const float4*)(qp + ((size_t)r << 5) + (h << 4));
    float4 qA = q4[0], qB = q4[1], qC = q4[2], qD = q4[3];
    const float4* ib2 = (const float4*)(in_b + 32 + (h << 4));
    float eb = dot4(qA, ib2[0]) + dot4(qB, ib2[1]) + dot4(qC, ib2[2]) + dot4(qD, ib2[3]);

    float lg[9];
    int nr[9];
    #pragma unroll
    for (int s = 0; s < 9; ++s) {
        int sy = y + DYC[s], sx = x + DXC[s];
        int tr = -1;
        if (sy >= 0 && sy < HH && sx >= 0 && sx < WW)
            tr = grid[(b << 18) + (sy << 9) + sx];
        nr[s] = tr;
        float d = eb;
        if (tr >= 0) {
            const float4* kp = (const float4*)(kv + ((size_t)tr << 6) + (h << 4));
            float4 k0 = kp[0], k1 = kp[1], k2 = kp[2], k3 = kp[3];
            d += dot4(qA, k0) + dot4(qB, k1) + dot4(qC, k2) + dot4(qD, k3);
        }
        lg[s] = d * 0.25f;   // 1/sqrt(HD=16)
    }
    float m = lg[0];
    #pragma unroll
    for (int s = 1; s < 9; ++s) m = fmaxf(m, lg[s]);
    float l = 0.f;
    #pragma unroll
    for (int s = 0; s < 9; ++s) { lg[s] = __expf(lg[s] - m); l += lg[s]; }

    float4 oA = {0,0,0,0}, oB = {0,0,0,0}, oC = {0,0,0,0}, oD = {0,0,0,0};
    float wdy = 0.f, wdx = 0.f, woc = 0.f;
    #pragma unroll
    for (int s = 0; s < 9; ++s) {
        if (nr[s] >= 0) {
            float wgt = lg[s];
            const float4* vp = (const float4*)(kv + ((size_t)nr[s] << 6) + 32 + (h << 4));
            float4 v0 = vp[0], v1 = vp[1], v2 = vp[2], v3 = vp[3];
            fma4(oA, wgt, v0); fma4(oB, wgt, v1); fma4(oC, wgt, v2); fma4(oD, wgt, v3);
            wdy += wgt * (float)DYC[s];
            wdx += wgt * (float)DXC[s];
            woc += wgt;
        }
    }
    float rl = 1.f / l;
    const float4* PY = (const float4*)(V + 96 + (h << 4));
    const float4* PX = (const float4*)(V + 128 + (h << 4));
    const float4* PB = (const float4*)(V + 160 + (h << 4));
    const float4* B3 = (const float4*)(in_b + 64 + (h << 4));
    float o16[16];
    ((float4*)o16)[0] = fin4(oA, wdy, wdx, woc, rl, PY[0], PX[0], PB[0], B3[0]);
    ((float4*)o16)[1] = fin4(oB, wdy, wdx, woc, rl, PY[1], PX[1], PB[1], B3[1]);
    ((float4*)o16)[2] = fin4(oC, wdy, wdx, woc, rl, PY[2], PX[2], PB[2], B3[2]);
    ((float4*)o16)[3] = fin4(oD, wdy, wdx, woc, rl, PY[3], PX[3], PB[3], B3[3]);

    // exchange halves with partner lane (head pair on adjacent lanes)
    float of0[16], of1[16];
    #pragma unroll
    for (int j = 0; j < 16; ++j) {
        float po = __shfl_xor(o16[j], 1, 64);
        of0[j] = h ? po : o16[j];
        of1[j] = h ? o16[j] : po;
    }

    // out projection: each lane computes only its own 16 output channels
    float acc[16];
    #pragma unroll
    for (int c = 0; c < 16; ++c) acc[c] = out_b[(h << 4) + c];
    #pragma unroll
    for (int j = 0; j < 16; ++j) {
        float v0 = of0[j];
        #pragma unroll
        for (int c = 0; c < 16; ++c) acc[c] += v0 * M[3072 + j * 32 + (h << 4) + c];
    }
    #pragma unroll
    for (int j = 0; j < 16; ++j) {
        float v1 = of1[j];
        #pragma unroll
        for (int c = 0; c < 16; ++c) acc[c] += v1 * M[3072 + (16 + j) * 32 + (h << 4) + c];
    }

    // stage to LDS: local point i row (stride 36 floats)
    int i = threadIdx.x >> 1;
    float* lrow = lds + i * 36 + (h << 4);
    #pragma unroll
    for (int k = 0; k < 4; ++k) ((float4*)lrow)[k] = ((float4*)acc)[k];
    __syncthreads();

    // stream out: per-instruction wave-contiguous 1 KB stores
    float* gbase = qp + (size_t)w * 4096;   // block covers points [w*128, +128) = 16 KB
    #pragma unroll
    for (int k = 0; k < 4; ++k) {
        int g = k * 1024 + threadIdx.x * 4;
        int ii = g >> 5, inner = g & 31;
        float4 val = *(const float4*)(lds + ii * 36 + inner);
        *(float4*)(gbase + g) = val;
    }
}

// ---------------- stage3: full-canvas write (rank reads are coalesced) ----------------
__global__ __launch_bounds__(256) void stage3(const int* __restrict__ grid,
                                              const float* __restrict__ obuf,
                                              float* __restrict__ out) {
    int w = (blockIdx.x & 7) * 256 + (blockIdx.x >> 3);   // G=2048, stripe-aligned with stage2
    int t = w * 256 + threadIdx.x;
    int b = t >> 18;
    int p = t & (HWPIX - 1);
    int rk = grid[t];
    float r[32];
    if (rk >= 0) {
        const float4* row = (const float4*)(obuf + ((size_t)rk << 5));
        #pragma unroll
        for (int i = 0; i < 8; ++i) ((float4*)r)[i] = row[i];
    } else {
        #pragma unroll
        for (int i = 0; i < 32; ++i) r[i] = 0.f;
    }
    float* outb = out + (size_t)b * CC * HWPIX + p;
    #pragma unroll
    for (int cc = 0; cc < 32; ++cc) outb[cc * HWPIX] = r[cc];
}

extern "C" void kernel_launch(void* const* d_in, const int* in_sizes, int n_in,
                              void* d_out, int out_size, void* d_ws, size_t ws_size,
                              hipStream_t stream) {
    const float* feats = (const float*)d_in[0];
    const int*   coors = (const int*)d_in[1];
    const float* ln_w  = (const float*)d_in[2];
    const float* ln_b  = (const float*)d_in[3];
    const float* wq    = (const float*)d_in[4];
    const float* bq    = (const float*)d_in[5];
    const float* wk    = (const float*)d_in[6];
    const float* bk    = (const float*)d_in[7];
    const float* wv    = (const float*)d_in[8];
    const float* bv    = (const float*)d_in[9];
    const float* pos_w = (const float*)d_in[10];
    const float* pos_b = (const float*)d_in[11];
    const float* in_w  = (const float*)d_in[12];
    const float* in_b  = (const float*)d_in[13];
    const float* out_w = (const float*)d_in[14];
    const float* out_b = (const float*)d_in[15];

    // workspace layout
    int*   grid = (int*)d_ws;                               // NPIX ints
    float* qp   = (float*)d_ws + NPIX;                      // NPTS*32 (reused as projected o)
    float* kv   = qp + (size_t)NPTS * 32;                   // NPTS*64 interleaved k|v
    float* M    = kv + (size_t)NPTS * 64;                   // 4096
    float* V    = M + 4096;                                 // 192
    size_t need = ((size_t)NPIX + (size_t)NPTS * 96 + 4096 + 192) * sizeof(float);
    if (ws_size < need) {
        fprintf(stderr, "kernel_launch: ws too small: %zu < %zu\n", ws_size, need);
        return;
    }
    // scratch in the tail of d_out (stage3 rewrites all of d_out at the end):
    //   [out_size-4096, -2048): cnt   [-2048, end): off
    //   [out_size-4096-2*NPTS, -4096): nlist | plist
    int* cnt   = (int*)d_out + (out_size - 4096);
    int* off   = cnt + 2048;
    int* nlist = (int*)d_out + (out_size - 4096 - 2 * NPTS);
    int* plist = nlist + NPTS;

    hipMemsetAsync(grid, 0xFF, (size_t)NPIX * sizeof(int), stream);   // grid = -1
    compose_mats<<<16, 256, 0, stream>>>(wq, wk, wv, in_w, out_w, M);
    compose_vecs<<<1, 128, 0, stream>>>(bq, bk, bv, in_w, in_b, pos_w, pos_b, V);
    build_grid<<<(NPTS + 255) / 256, 256, 0, stream>>>(coors, grid);
    count_occ<<<NBLK, 256, 0, stream>>>(grid, cnt);
    scan2048<<<1, 256, 0, stream>>>(cnt, off);
    assign_ranks<<<NBLK, 256, 0, stream>>>(off, grid, nlist, plist);
    stage1<<<944, 256, 0, stream>>>(feats, ln_w, ln_b, M, V, nlist, qp, kv);
    stage2<<<1880, 256, 0, stream>>>(grid, plist, kv, M, V, in_b, out_b, qp);
    stage3<<<NBLK, 256, 0, stream>>>(grid, qp, (float*)d_out);
}

// Round 6
// 232.660 us; speedup vs baseline: 1.1019x; 1.0576x over previous
//
#include <hip/hip_runtime.h>
#include <hip/hip_fp16.h>
#include <cstdio>
#include <cstdint>

#define HH 512
#define WW 512
#define CC 32
#define BB 2
#define NN 120000
#define HWPIX (HH*WW)
#define NPTS (BB*NN)          // 240000 == total ranks (every point has a unique pixel)
#define NPIX (BB*HWPIX)       // 524288
#define NBLK (NPIX/256)       // 2048

__device__ __forceinline__ void h8_to_f8(float4 raw, float* o) {
    const __half2* h = (const __half2*)&raw;
    #pragma unroll
    for (int i = 0; i < 4; ++i) {
        float2 f = __half22float2(h[i]);
        o[2 * i] = f.x; o[2 * i + 1] = f.y;
    }
}

// ---------------- compose fused weight matrices ----------------
// M layout (floats): [0:1024) MqT, [1024:2048) MkT, [2048:3072) MvT, [3072:4096) owT
// MxT[j*32+c'] = (W_proj @ w_x)[c'][j];  owT[j*32+c'] = out_w[c'][j]
__global__ void compose_mats(const float* __restrict__ wq, const float* __restrict__ wk,
                             const float* __restrict__ wv, const float* __restrict__ in_w,
                             const float* __restrict__ out_w, float* __restrict__ M) {
    int tid = blockIdx.x * blockDim.x + threadIdx.x;   // 0..4095
    if (tid >= 4096) return;
    int which = tid >> 10;
    int e = tid & 1023;
    int cp = e & 31;
    int j  = e >> 5;
    if (which < 3) {
        const float* w = (which == 0) ? wq : ((which == 1) ? wk : wv);
        const float* Wrow = in_w + (which * 32 + cp) * 32;
        float acc = 0.f;
        #pragma unroll
        for (int t = 0; t < 32; ++t) acc += Wrow[t] * w[t * 32 + j];
        M[which * 1024 + j * 32 + cp] = acc;
    } else {
        M[3 * 1024 + j * 32 + cp] = out_w[cp * 32 + j];
    }
}

// V layout (floats): [0:32) bq' = W1@bq + in_b[:32], [32:64) bk' = W2@bk, [64:96) bv' = W3@bv,
// [96:128) PWy[c] = (W3@pos_w)[c][0], [128:160) PWx[c] = (W3@pos_w)[c][1], [160:192) pb3 = W3@pos_b
__global__ void compose_vecs(const float* __restrict__ bq, const float* __restrict__ bk,
                             const float* __restrict__ bv, const float* __restrict__ in_w,
                             const float* __restrict__ in_b, const float* __restrict__ pos_w,
                             const float* __restrict__ pos_b, float* __restrict__ V) {
    int tid = threadIdx.x;
    if (tid < 32) {
        float a = 0.f, b = 0.f, c = 0.f;
        #pragma unroll
        for (int t = 0; t < 32; ++t) {
            a += in_w[tid * 32 + t] * bq[t];
            b += in_w[(32 + tid) * 32 + t] * bk[t];
            c += in_w[(64 + tid) * 32 + t] * bv[t];
        }
        V[tid]      = a + in_b[tid];
        V[32 + tid] = b;
        V[64 + tid] = c;
    } else if (tid < 128) {
        int grp = (tid - 32) >> 5;   // 0=PWy 1=PWx 2=pb3
        int cp  = tid & 31;
        float acc = 0.f;
        #pragma unroll
        for (int t = 0; t < 32; ++t) {
            float src = (grp == 0) ? pos_w[t * 2 + 0] : ((grp == 1) ? pos_w[t * 2 + 1] : pos_b[t]);
            acc += in_w[(64 + cp) * 32 + t] * src;
        }
        V[96 + grp * 32 + cp] = acc;
    }
}

// ---------------- dense coord -> point-index grid ----------------
__global__ void build_grid(const int* __restrict__ coors, int* __restrict__ grid) {
    int P = blockIdx.x * blockDim.x + threadIdx.x;
    if (P >= NPTS) return;
    int b = P / NN;
    int n = P - b * NN;
    int y = coors[P * 2 + 0];
    int x = coors[P * 2 + 1];
    grid[b * HWPIX + y * WW + x] = n;
}

// ---------------- per-window occupied count ----------------
__global__ __launch_bounds__(256) void count_occ(const int* __restrict__ grid, int* __restrict__ cnt) {
    int tid = threadIdx.x;
    int pix = blockIdx.x * 256 + tid;
    bool occ = grid[pix] >= 0;
    unsigned long long mask = __ballot(occ);
    __shared__ int w[4];
    if ((tid & 63) == 0) w[tid >> 6] = __popcll(mask);
    __syncthreads();
    if (tid == 0) cnt[blockIdx.x] = w[0] + w[1] + w[2] + w[3];
}

// ---------------- exclusive scan of 2048 counts (single block) ----------------
__global__ __launch_bounds__(256) void scan2048(const int* __restrict__ cnt, int* __restrict__ off) {
    __shared__ int ps[256];
    int tid = threadIdx.x;
    int v[8], loc[8];
    int t = 0;
    #pragma unroll
    for (int k = 0; k < 8; ++k) { v[k] = cnt[tid * 8 + k]; loc[k] = t; t += v[k]; }
    ps[tid] = t;
    __syncthreads();
    for (int d = 1; d < 256; d <<= 1) {
        int val = ps[tid];
        int add = (tid >= d) ? ps[tid - d] : 0;
        __syncthreads();
        ps[tid] = val + add;
        __syncthreads();
    }
    int excl = (tid > 0) ? ps[tid - 1] : 0;
    #pragma unroll
    for (int k = 0; k < 8; ++k) off[tid * 8 + k] = excl + loc[k];
}

// ---------------- assign ranks: grid[pix]=rank, rmap[point]=rank, plist[rank]=pix ----------------
__global__ __launch_bounds__(256) void assign_ranks(const int* __restrict__ off,
                                                    int* __restrict__ grid,
                                                    int* __restrict__ rmap,
                                                    int* __restrict__ plist) {
    __shared__ int woff[4];
    int tid = threadIdx.x;
    int pix = blockIdx.x * 256 + tid;
    int n = grid[pix];
    bool occ = n >= 0;
    unsigned long long mask = __ballot(occ);
    int lane = tid & 63, wvi = tid >> 6;
    if (lane == 0) woff[wvi] = __popcll(mask);
    __syncthreads();
    int pre = 0;
    for (int w = 0; w < wvi; ++w) pre += woff[w];
    if (occ) {
        int r = off[blockIdx.x] + pre + __popcll(mask & ((1ull << lane) - 1ull));
        grid[pix] = r;
        rmap[(pix >> 18) * NN + n] = r;
        plist[r] = pix;
    }
}

// ---------------- stage1: point-parallel LN + fused q/k/v linears ----------------
// Coalesced feats reads (point order); scattered full-line writes to rank slots.
// qp[rank] fp32 (128 B); kvh[rank] = 32 half k | 32 half v (128 B).
__global__ __launch_bounds__(256) void stage1(const float* __restrict__ feats,
                                              const float* __restrict__ ln_w,
                                              const float* __restrict__ ln_b,
                                              const float* __restrict__ M,
                                              const float* __restrict__ V,
                                              const int* __restrict__ rmap,
                                              float* __restrict__ qp,
                                              __half* __restrict__ kvh) {
    int gp = blockIdx.x * 256 + threadIdx.x;
    if (gp >= NPTS) return;
    int r = rmap[gp];

    const float* fr = feats + ((size_t)gp << 5);
    float x[32];
    #pragma unroll
    for (int k = 0; k < 8; ++k) ((float4*)x)[k] = ((const float4*)fr)[k];

    float s1 = 0.f, s2 = 0.f;
    #pragma unroll
    for (int j = 0; j < 32; ++j) { s1 += x[j]; s2 += x[j] * x[j]; }
    float mu   = s1 * (1.f / 32.f);
    float var  = s2 * (1.f / 32.f) - mu * mu;
    float rstd = rsqrtf(var + 1e-5f);
    #pragma unroll
    for (int j = 0; j < 32; ++j) x[j] = (x[j] - mu) * rstd * ln_w[j] + ln_b[j];

    float acc[32];

    // q' = x @ Mq + bq'  (fp32)
    #pragma unroll
    for (int c = 0; c < 32; ++c) acc[c] = V[c];
    #pragma unroll
    for (int j = 0; j < 32; ++j) {
        float xv = x[j];
        #pragma unroll
        for (int c = 0; c < 32; ++c) acc[c] += xv * M[j * 32 + c];
    }
    {
        float4* qd = (float4*)(qp + ((size_t)r << 5));
        #pragma unroll
        for (int k = 0; k < 8; ++k) qd[k] = ((float4*)acc)[k];
    }

    __half2 kvbuf[32];   // 128 B: k halves [0:16), v halves [16:32)

    // k' = x @ Mk + bk'  -> fp16
    #pragma unroll
    for (int c = 0; c < 32; ++c) acc[c] = V[32 + c];
    #pragma unroll
    for (int j = 0; j < 32; ++j) {
        float xv = x[j];
        #pragma unroll
        for (int c = 0; c < 32; ++c) acc[c] += xv * M[1024 + j * 32 + c];
    }
    #pragma unroll
    for (int c = 0; c < 16; ++c) kvbuf[c] = __floats2half2_rn(acc[2 * c], acc[2 * c + 1]);

    // v' = x @ Mv + bv'  -> fp16
    #pragma unroll
    for (int c = 0; c < 32; ++c) acc[c] = V[64 + c];
    #pragma unroll
    for (int j = 0; j < 32; ++j) {
        float xv = x[j];
        #pragma unroll
        for (int c = 0; c < 32; ++c) acc[c] += xv * M[2048 + j * 32 + c];
    }
    #pragma unroll
    for (int c = 0; c < 16; ++c) kvbuf[16 + c] = __floats2half2_rn(acc[2 * c], acc[2 * c + 1]);

    float4* kd = (float4*)(kvh + ((size_t)r << 6));
    #pragma unroll
    for (int k = 0; k < 8; ++k) kd[k] = ((float4*)kvbuf)[k];
}

// ---------------- stage2: dense (rank,head)-parallel attention + out-proj ----------------
// Thread pair (even,odd lane) = the two heads of one point. fp16 kv gather; out-proj
// with wave-uniform (scalarized) weights; output staged through LDS for contiguous stores.
// Overwrites qp[rank] with the projected output row.
__global__ __launch_bounds__(256) void stage2(const int* __restrict__ grid,
                                              const int* __restrict__ plist,
                                              const __half* __restrict__ kvh,
                                              const float* __restrict__ M,
                                              const float* __restrict__ V,
                                              const float* __restrict__ in_b,
                                              const float* __restrict__ out_b,
                                              float* __restrict__ qp) {
    __shared__ float lds[128 * 36];   // 18 KB; row stride 36 keeps float4 alignment

    int w = (blockIdx.x & 7) * 235 + (blockIdx.x >> 3);   // G=1880; XCD x -> ranks [x*30080, +30080)
    if (w >= 1875) return;                                 // 1875*256 == 2*NPTS exactly
    int t = w * 256 + threadIdx.x;
    int r = t >> 1, h = t & 1;

    int pix = plist[r];
    int b = pix >> 18;
    int p = pix & (HWPIX - 1);
    int y = p >> 9, x = p & 511;

    const int DYC[9] = {0,-1,1,0,-1,1,0,-1,1};
    const int DXC[9] = {0,0,0,1,1,1,-1,-1,-1};

    float qf[16];
    {
        const float4* q4 = (const float4*)(qp + ((size_t)r << 5) + (h << 4));
        #pragma unroll
        for (int k = 0; k < 4; ++k) ((float4*)qf)[k] = q4[k];
    }
    float ebv = 0.f;
    {
        const float* ib = in_b + 32 + (h << 4);
        #pragma unroll
        for (int i = 0; i < 16; ++i) ebv += qf[i] * ib[i];
    }

    // all 9 grid lookups issued before any dependent kv load
    int nr[9];
    #pragma unroll
    for (int s = 0; s < 9; ++s) {
        int sy = y + DYC[s], sx = x + DXC[s];
        nr[s] = (sy >= 0 && sy < HH && sx >= 0 && sx < WW) ? grid[(b << 18) + (sy << 9) + sx] : -1;
    }

    float lg[9];
    #pragma unroll
    for (int s = 0; s < 9; ++s) {
        float d = ebv;
        if (nr[s] >= 0) {
            const float4* kp = (const float4*)(kvh + ((size_t)nr[s] << 6) + (h << 4));
            float kf[16];
            h8_to_f8(kp[0], kf); h8_to_f8(kp[1], kf + 8);
            #pragma unroll
            for (int i = 0; i < 16; ++i) d += qf[i] * kf[i];
        }
        lg[s] = d * 0.25f;   // 1/sqrt(HD=16)
    }
    float m = lg[0];
    #pragma unroll
    for (int s = 1; s < 9; ++s) m = fmaxf(m, lg[s]);
    float l = 0.f;
    #pragma unroll
    for (int s = 0; s < 9; ++s) { lg[s] = __expf(lg[s] - m); l += lg[s]; }

    float o16[16];
    #pragma unroll
    for (int i = 0; i < 16; ++i) o16[i] = 0.f;
    float wdy = 0.f, wdx = 0.f, woc = 0.f;
    #pragma unroll
    for (int s = 0; s < 9; ++s) {
        if (nr[s] >= 0) {
            float wgt = lg[s];
            const float4* vp = (const float4*)(kvh + ((size_t)nr[s] << 6) + 32 + (h << 4));
            float vf[16];
            h8_to_f8(vp[0], vf); h8_to_f8(vp[1], vf + 8);
            #pragma unroll
            for (int i = 0; i < 16; ++i) o16[i] += wgt * vf[i];
            wdy += wgt * (float)DYC[s];
            wdx += wgt * (float)DXC[s];
            woc += wgt;
        }
    }
    float rl = 1.f / l;
    {
        const float* PY = V + 96 + (h << 4);
        const float* PX = V + 128 + (h << 4);
        const float* PB = V + 160 + (h << 4);
        const float* B3 = in_b + 64 + (h << 4);
        #pragma unroll
        for (int i = 0; i < 16; ++i)
            o16[i] = (o16[i] + wdy * PY[i] + wdx * PX[i] + woc * PB[i]) * rl + B3[i];
    }

    // exchange halves with partner lane -> full 32-dim o on both lanes
    float of[32];
    #pragma unroll
    for (int j = 0; j < 16; ++j) {
        float po = __shfl_xor(o16[j], 1, 64);
        of[j]      = h ? po : o16[j];
        of[16 + j] = h ? o16[j] : po;
    }

    // out projection: all 32 channels with wave-uniform (scalarized) weights, keep own half
    float acc[32];
    #pragma unroll
    for (int c = 0; c < 32; ++c) acc[c] = out_b[c];
    #pragma unroll
    for (int j = 0; j < 32; ++j) {
        float vj = of[j];
        #pragma unroll
        for (int c = 0; c < 32; ++c) acc[c] += vj * M[3072 + j * 32 + c];
    }
    float st[16];
    #pragma unroll
    for (int k = 0; k < 16; ++k) st[k] = h ? acc[16 + k] : acc[k];

    // stage to LDS: local point i row (stride 36 floats)
    int i = threadIdx.x >> 1;
    float* lrow = lds + i * 36 + (h << 4);
    #pragma unroll
    for (int k = 0; k < 4; ++k) ((float4*)lrow)[k] = ((float4*)st)[k];
    __syncthreads();

    // stream out: per-instruction wave-contiguous 1 KB stores
    float* gbase = qp + (size_t)w * 4096;   // block covers points [w*128, +128) = 16 KB
    #pragma unroll
    for (int k = 0; k < 4; ++k) {
        int g = k * 1024 + threadIdx.x * 4;
        int ii = g >> 5, inner = g & 31;
        float4 val = *(const float4*)(lds + ii * 36 + inner);
        *(float4*)(gbase + g) = val;
    }
}

// ---------------- stage3: full-canvas write (rank reads are coalesced) ----------------
__global__ __launch_bounds__(256) void stage3(const int* __restrict__ grid,
                                              const float* __restrict__ obuf,
                                              float* __restrict__ out) {
    int w = (blockIdx.x & 7) * 256 + (blockIdx.x >> 3);   // G=2048, stripe-aligned with stage2
    int t = w * 256 + threadIdx.x;
    int b = t >> 18;
    int p = t & (HWPIX - 1);
    int rk = grid[t];
    float r[32];
    if (rk >= 0) {
        const float4* row = (const float4*)(obuf + ((size_t)rk << 5));
        #pragma unroll
        for (int i = 0; i < 8; ++i) ((float4*)r)[i] = row[i];
    } else {
        #pragma unroll
        for (int i = 0; i < 32; ++i) r[i] = 0.f;
    }
    float* outb = out + (size_t)b * CC * HWPIX + p;
    #pragma unroll
    for (int cc = 0; cc < 32; ++cc) outb[cc * HWPIX] = r[cc];
}

extern "C" void kernel_launch(void* const* d_in, const int* in_sizes, int n_in,
                              void* d_out, int out_size, void* d_ws, size_t ws_size,
                              hipStream_t stream) {
    const float* feats = (const float*)d_in[0];
    const int*   coors = (const int*)d_in[1];
    const float* ln_w  = (const float*)d_in[2];
    const float* ln_b  = (const float*)d_in[3];
    const float* wq    = (const float*)d_in[4];
    const float* bq    = (const float*)d_in[5];
    const float* wk    = (const float*)d_in[6];
    const float* bk    = (const float*)d_in[7];
    const float* wv    = (const float*)d_in[8];
    const float* bv    = (const float*)d_in[9];
    const float* pos_w = (const float*)d_in[10];
    const float* pos_b = (const float*)d_in[11];
    const float* in_w  = (const float*)d_in[12];
    const float* in_b  = (const float*)d_in[13];
    const float* out_w = (const float*)d_in[14];
    const float* out_b = (const float*)d_in[15];

    // workspace layout
    int*    grid = (int*)d_ws;                              // NPIX ints
    float*  qp   = (float*)d_ws + NPIX;                     // NPTS*32 fp32 (reused as projected o)
    __half* kvh  = (__half*)((float*)d_ws + NPIX + (size_t)NPTS * 32);  // NPTS*64 halves (k|v)
    float*  M    = (float*)(kvh + (size_t)NPTS * 64);       // 4096
    float*  V    = M + 4096;                                // 192
    size_t need = ((size_t)NPIX + (size_t)NPTS * 32 + (size_t)NPTS * 16 + 4096 + 192) * sizeof(float);
    if (ws_size < need) {
        fprintf(stderr, "kernel_launch: ws too small: %zu < %zu\n", ws_size, need);
        return;
    }
    // scratch in the tail of d_out (stage3 rewrites all of d_out at the end):
    int* cnt   = (int*)d_out + (out_size - 4096);
    int* off   = cnt + 2048;
    int* rmap  = (int*)d_out + (out_size - 4096 - 2 * NPTS);
    int* plist = rmap + NPTS;

    hipMemsetAsync(grid, 0xFF, (size_t)NPIX * sizeof(int), stream);   // grid = -1
    compose_mats<<<16, 256, 0, stream>>>(wq, wk, wv, in_w, out_w, M);
    compose_vecs<<<1, 128, 0, stream>>>(bq, bk, bv, in_w, in_b, pos_w, pos_b, V);
    build_grid<<<(NPTS + 255) / 256, 256, 0, stream>>>(coors, grid);
    count_occ<<<NBLK, 256, 0, stream>>>(grid, cnt);
    scan2048<<<1, 256, 0, stream>>>(cnt, off);
    assign_ranks<<<NBLK, 256, 0, stream>>>(off, grid, rmap, plist);
    stage1<<<(NPTS + 255) / 256, 256, 0, stream>>>(feats, ln_w, ln_b, M, V, rmap, qp, kvh);
    stage2<<<1880, 256, 0, stream>>>(grid, plist, kvh, M, V, in_b, out_b, qp);
    stage3<<<NBLK, 256, 0, stream>>>(grid, qp, (float*)d_out);
}